// Round 4
// baseline (5421.308 us; speedup 1.0000x reference)
//
#include <hip/hip_runtime.h>
#include <stdint.h>
#include <stddef.h>

// Problem dims
#define B_ 1024
#define S_ 128
#define D_ 256
#define H_ 2048
#define O_ 10
#define V_ 10

// Step-GEMM: C[1024 x 2048] = Hin[1024 x 2048(K)] * W[2048(N) x 2048(K)]^T
// K-split g=2: grid 256 = 8(m) x 16(n) x 2(k). WG = 128x128 tile, K-range 1024.
// 4 waves of 64x64 (acc 4x4) -> LDS reuse 0.0625 B/MAC (2x better than 32x32).
// The two k-WGs of a pair exchange f32 partials in-kernel (agent-scope flag).
#define BM 128
#define BN 128
#define BK 64
#define KR 1024          // K-range per WG
#define NKT (KR / BK)    // 16 K-iterations

typedef unsigned short u16;
typedef short v8s __attribute__((ext_vector_type(8)));    // 8 x bf16 (4 VGPRs) MFMA A/B frag
typedef float v4f __attribute__((ext_vector_type(4)));    // 4 x f32 MFMA C/D frag
typedef u16 u16x4 __attribute__((ext_vector_type(4)));

__device__ __forceinline__ u16 f2bf(float f) {
  unsigned int u = __float_as_uint(f);
  u += 0x7FFFu + ((u >> 16) & 1u);   // RNE
  return (u16)(u >> 16);
}
__device__ __forceinline__ float bf2f(u16 h) {
  return __uint_as_float(((unsigned int)h) << 16);
}
__device__ __forceinline__ float fast_tanh(float x) {
  float e = __expf(2.0f * x);
  return 1.0f - 2.0f / (e + 1.0f);
}
__device__ __forceinline__ void gl2lds16(const void* g, void* l) {
  __builtin_amdgcn_global_load_lds(
      (const __attribute__((address_space(1))) uint32_t*)g,
      (__attribute__((address_space(3))) uint32_t*)l, 16, 0, 0);
}

// ---------------- zero the handshake flags (runs every call; ws is re-poisoned) ----
__global__ void zero_flags(int* __restrict__ flags) {
  flags[threadIdx.x] = 0;
}

// ---------------- Txh[v][h] = b_hx[h] + sum_d embed[v][d]*W_hx[h][d] ----------------
__global__ __launch_bounds__(256) void make_table(const float* __restrict__ embed,
                                                  const float* __restrict__ W_hx,
                                                  const float* __restrict__ b_hx,
                                                  float* __restrict__ Txh) {
  int idx = blockIdx.x * 256 + threadIdx.x;   // 10*2048 = 20480
  int v = idx >> 11, h = idx & 2047;
  const float4* e4 = (const float4*)(embed + v * D_);
  const float4* w4 = (const float4*)(W_hx + (size_t)h * D_);
  float s = b_hx[h];
#pragma unroll 4
  for (int d = 0; d < D_ / 4; ++d) {
    float4 a = e4[d], b = w4[d];
    s = fmaf(a.x, b.x, s); s = fmaf(a.y, b.y, s);
    s = fmaf(a.z, b.z, s); s = fmaf(a.w, b.w, s);
  }
  Txh[idx] = s;
}

// ---------------- W_hh (f32) -> bf16, same [N][K] layout ----------------
__global__ __launch_bounds__(256) void conv_w(const float* __restrict__ W,
                                              u16* __restrict__ Wb) {
  int i = blockIdx.x * 256 + threadIdx.x;     // over 4M/4 = 1M float4
  float4 w = ((const float4*)W)[i];
  u16x4 o = { f2bf(w.x), f2bf(w.y), f2bf(w.z), f2bf(w.w) };
  ((u16x4*)Wb)[i] = o;
}

// ---------------- h0[b][j] = tanh(Txh[x[b,0]][j])  (no b_hh at step 0) ----------------
__global__ __launch_bounds__(256) void init_h0(const float* __restrict__ Txh,
                                               const int* __restrict__ x,
                                               u16* __restrict__ H0) {
  int idx = blockIdx.x * 256 + threadIdx.x;   // 1024*2048 = 2M
  int b = idx >> 11, j = idx & 2047;
  int xv = x[b * S_];
  H0[idx] = f2bf(fast_tanh(Txh[xv * H_ + j]));
}

// ---------------- staging: 128 rows x 8 chunks(16B) = 1024 slots, 4 issues ----------
// LDS layout [row][8 chunks], chunk XOR-swizzled: slot(r,c) = r*8 + (c^(r&7)).
__device__ __forceinline__ void stage_tile(const u16* __restrict__ src,
                                           u16* __restrict__ dst,
                                           int row0, int kbase, int tid, int w) {
#pragma unroll
  for (int i = 0; i < 4; ++i) {
    int s = i * 256 + tid;
    int r = s >> 3;
    int c = (s & 7) ^ (r & 7);                // swizzle applied on the global side
    const u16* g = src + (size_t)(row0 + r) * H_ + kbase + c * 8;
    u16* lp = dst + (size_t)(i * 256 + (w << 6)) * 8;  // wave-uniform base; lane at +l*16B
    gl2lds16(g, lp);
  }
}

// ---------------- one recurrence step (K-split pair with in-kernel combine) --------
__global__ __launch_bounds__(256, 2) void rnn_step(const u16* __restrict__ Hin,
                                                   const u16* __restrict__ Wb,
                                                   const float* __restrict__ Txh,
                                                   const int* __restrict__ x,
                                                   const float* __restrict__ b_hh,
                                                   u16* __restrict__ Hout,
                                                   float* Cpart, int* flags,
                                                   int t) {
  __shared__ __align__(16) u16 As[2][BM * BK];   // 2 x 16 KB
  __shared__ __align__(16) u16 Bs[2][BN * BK];   // 2 x 16 KB

  const int tid = threadIdx.x;
  const int bid = blockIdx.x;
  // XCD-paired mapping: xcd = bid&7; slot = bid>>3 (0..31); k = slot&1; ps = slot>>1.
  // Pair (m,n) lives entirely on one XCD (both k's). Per-XCD L2: A 2MB + W 2MB.
  const int xcd = bid & 7;
  const int slot = bid >> 3;
  const int kwg = slot & 1;
  const int ps = slot >> 1;                    // 0..15
  const int mg = (xcd >> 2) * 4 + (ps >> 2);   // 0..7
  const int ng = (xcd & 3) * 4 + (ps & 3);     // 0..15
  const int pair = mg * 16 + ng;               // 0..127
  const int bm = mg * BM, bn = ng * BN;
  const int kbase0 = kwg * KR;

  const int w = tid >> 6, l = tid & 63;
  const int wr = w >> 1, wc = w & 1;           // wave tile origin: (wr*64, wc*64)
  const int lane16 = l & 15, quad = l >> 4;

  v4f acc[4][4];
#pragma unroll
  for (int i = 0; i < 4; ++i)
#pragma unroll
    for (int j = 0; j < 4; ++j) acc[i][j] = (v4f){0.f, 0.f, 0.f, 0.f};

  stage_tile(Hin, As[0], bm, kbase0, tid, w);
  stage_tile(Wb,  Bs[0], bn, kbase0, tid, w);
  __syncthreads();

  for (int kt = 0; kt < NKT; ++kt) {
    const int cur = kt & 1;
    if (kt + 1 < NKT) {
      stage_tile(Hin, As[cur ^ 1], bm, kbase0 + (kt + 1) * BK, tid, w);
      stage_tile(Wb,  Bs[cur ^ 1], bn, kbase0 + (kt + 1) * BK, tid, w);
    }

#pragma unroll
    for (int kc = 0; kc < 2; ++kc) {
      const int cc = kc * 4 + quad;            // chunk index within row (0..7)
      v8s a[4], bf[4];
#pragma unroll
      for (int i = 0; i < 4; ++i) {
        int m = wr * 64 + i * 16 + lane16;
        a[i] = *(const v8s*)&As[cur][(m * 8 + (cc ^ (m & 7))) * 8];
      }
#pragma unroll
      for (int j = 0; j < 4; ++j) {
        int n = wc * 64 + j * 16 + lane16;
        bf[j] = *(const v8s*)&Bs[cur][(n * 8 + (cc ^ (n & 7))) * 8];
      }
#pragma unroll
      for (int i = 0; i < 4; ++i)
#pragma unroll
        for (int j = 0; j < 4; ++j)
          acc[i][j] = __builtin_amdgcn_mfma_f32_16x16x32_bf16(a[i], bf[j], acc[i][j], 0, 0, 0);
    }
    __syncthreads();
  }

  // ---- partial exchange: WG kwg's waves with wr != kwg write their 64x128 half ----
  // Cpart[kwg][pair] holds the half-tile the partner WG will consume.
  // C/D layout: col = lane&15, row = quad*4 + reg  [m89-verified]
  float* myhalf = Cpart + ((size_t)(kwg * 128 + pair)) * (64 * 128);
  if (wr != kwg) {
#pragma unroll
    for (int i = 0; i < 4; ++i) {
#pragma unroll
      for (int r = 0; r < 4; ++r) {
        int rl = i * 16 + quad * 4 + r;        // row within the 64-row half
#pragma unroll
        for (int j = 0; j < 4; ++j) {
          int cl = wc * 64 + j * 16 + lane16;
          myhalf[rl * 128 + cl] = acc[i][j][r];
        }
      }
    }
  }
  __syncthreads();
  if (tid == 0) {
    __threadfence();
    __hip_atomic_fetch_add(&flags[pair], 1, __ATOMIC_RELEASE, __HIP_MEMORY_SCOPE_AGENT);
    const int target = 2 * t;                  // both WGs of the pair posted this step
    while (__hip_atomic_load(&flags[pair], __ATOMIC_ACQUIRE, __HIP_MEMORY_SCOPE_AGENT) < target)
      __builtin_amdgcn_s_sleep(1);
  }
  __syncthreads();

  // ---- combine + epilogue: waves with wr == kwg own rows kwg*64 .. +64 ----
  if (wr == kwg) {
    const float* phalf = Cpart + ((size_t)((1 - kwg) * 128 + pair)) * (64 * 128);
    const int colb = bn + wc * 64 + lane16;
    float bh[4];
#pragma unroll
    for (int j = 0; j < 4; ++j) bh[j] = b_hh[colb + j * 16];
#pragma unroll
    for (int i = 0; i < 4; ++i) {
#pragma unroll
      for (int r = 0; r < 4; ++r) {
        int rl = i * 16 + quad * 4 + r;        // row within my 64-row half
        int row = bm + kwg * 64 + rl;
        const float* trow = Txh + x[row * S_ + t] * H_;
        u16* orow = Hout + (size_t)row * H_;
#pragma unroll
        for (int j = 0; j < 4; ++j) {
          int cl = wc * 64 + j * 16 + lane16;
          int col = bn + cl;
          float v = acc[i][j][r] + phalf[rl * 128 + cl] + trow[col] + bh[j - 0];
          orow[col] = f2bf(fast_tanh(v));
        }
      }
    }
  }
}

// ---------------- o = hT @ W_oh^T + b_oh ; softmax over 10 ----------------
__global__ __launch_bounds__(256) void out_softmax(const u16* __restrict__ Hf,
                                                   const float* __restrict__ W_oh,
                                                   const float* __restrict__ b_oh,
                                                   float* __restrict__ out) {
  int b = blockIdx.x, tid = threadIdx.x;
  float hv[8];
  const u16* hr = Hf + (size_t)b * H_ + tid * 8;
#pragma unroll
  for (int u = 0; u < 8; ++u) hv[u] = bf2f(hr[u]);
  float acc[O_];
#pragma unroll
  for (int i = 0; i < O_; ++i) {
    const float* wr = W_oh + (size_t)i * H_ + tid * 8;
    float s = 0.f;
#pragma unroll
    for (int u = 0; u < 8; ++u) s = fmaf(hv[u], wr[u], s);
    acc[i] = s;
  }
#pragma unroll
  for (int off = 32; off > 0; off >>= 1)
#pragma unroll
    for (int i = 0; i < O_; ++i) acc[i] += __shfl_down(acc[i], off);
  __shared__ float red[4][O_];
  if ((tid & 63) == 0)
#pragma unroll
    for (int i = 0; i < O_; ++i) red[tid >> 6][i] = acc[i];
  __syncthreads();
  if (tid == 0) {
    float o[O_], mx = -1e30f;
#pragma unroll
    for (int i = 0; i < O_; ++i) {
      o[i] = red[0][i] + red[1][i] + red[2][i] + red[3][i] + b_oh[i];
      mx = fmaxf(mx, o[i]);
    }
    float se = 0.f;
#pragma unroll
    for (int i = 0; i < O_; ++i) { o[i] = __expf(o[i] - mx); se += o[i]; }
    float inv = 1.f / se;
#pragma unroll
    for (int i = 0; i < O_; ++i) out[b * O_ + i] = o[i] * inv;
  }
}

extern "C" void kernel_launch(void* const* d_in, const int* in_sizes, int n_in,
                              void* d_out, int out_size, void* d_ws, size_t ws_size,
                              hipStream_t stream) {
  const int*   x     = (const int*)  d_in[0];
  const float* embed = (const float*)d_in[1];
  const float* b_hx  = (const float*)d_in[3];
  const float* W_hx  = (const float*)d_in[2];
  const float* W_hh  = (const float*)d_in[4];
  const float* b_hh  = (const float*)d_in[5];
  const float* W_oh  = (const float*)d_in[6];
  const float* b_oh  = (const float*)d_in[7];
  float* out = (float*)d_out;

  // workspace: Txh 80KB | Wb 8MB | Ha 4MB | Hb 4MB | Cpart 8MB | flags 512B (~24.1 MB)
  char* ws = (char*)d_ws;
  float* Txh  = (float*)ws;
  u16* Wb     = (u16*)(ws + (80 << 10));
  u16* Ha     = (u16*)(ws + (80 << 10) + (8 << 20));
  u16* Hb     = (u16*)(ws + (80 << 10) + (12 << 20));
  float* Cpart= (float*)(ws + (80 << 10) + (16 << 20));
  int* flags  = (int*)(ws + (80 << 10) + (24 << 20));

  zero_flags<<<1, 128, 0, stream>>>(flags);
  make_table<<<80, 256, 0, stream>>>(embed, W_hx, b_hx, Txh);
  conv_w<<<4096, 256, 0, stream>>>(W_hh, Wb);
  init_h0<<<8192, 256, 0, stream>>>(Txh, x, Ha);

  for (int t = 1; t < S_; ++t) {
    const u16* hin = (t & 1) ? Ha : Hb;
    u16* hout = (t & 1) ? Hb : Ha;
    rnn_step<<<256, 256, 0, stream>>>(hin, Wb, Txh, x, b_hh, hout, Cpart, flags, t);
  }
  // t=127 (odd) wrote Hb
  out_softmax<<<B_, 256, 0, stream>>>(Hb, W_oh, b_oh, out);
}